// Round 12
// baseline (656.885 us; speedup 1.0000x reference)
//
#include <hip/hip_runtime.h>
#include <cstdint>
#include <cstddef>

// ---------------- constants ----------------
#define BATCH   32768
#define BT      4            // samples per workgroup
#define S1      9            // SLOTS+1
#define RROWS   36           // BT*S1
#define NBLK    (BATCH/BT)   // 8192

// d_ws byte offsets (bf16 transposed weights + collapsed MLP)
#define WS_WIN   0            // [128][128] bf16  WinT[n][k] = W_in[k][n]
#define WS_WQKV  32768        // [384][128] bf16
#define WS_WC    131072       // [128][128] bf16  (W_m1 @ W_m2)^T
#define WS_WGI   163840       // [256][128] bf16
#define WS_WGM   229376       // [256][128] bf16
#define WS_BC    294912       // [128] f32        b_m1 @ W_m2 + b_m2

// LDS plan (37888 B; 4 blocks/CU under launch_bounds(256,4)):
//  Q [0,27648)      qkv bf16 [36][768B] swz. P4a: P f32 (36B) into dead q-slices;
//                   P4b: attn-out bf16 (64B) into dead K-slices (cb+64). Later:
//                   mlp f32 [36][512B] @0 (P6); mem2 bf16 [32][256B] @19456 (P7);
//                   gib f32 [4][1024B] @0 (P8, over dead mlp rows 0..7).
//  A [27648,36864)  amp bf16 [36][256B] swz: mp -> mem (P5 in place) -> tanh(memory) (P8).
//  X [36864,37888)  x bf16 [4][256B] swz: staged inputs -> x (P1 in place).
// No zero padding: A-fragment rows CLAMPED (dups only feed discarded C rows).
#define A_OFF  27648
#define X_OFF  36864
#define MEM2   19456
#define LDSSZ  37888

typedef __bf16 bf16x8 __attribute__((ext_vector_type(8), may_alias));
typedef __bf16 bf16x4 __attribute__((ext_vector_type(4), may_alias));
typedef float  f32x4  __attribute__((ext_vector_type(4), may_alias));
typedef __bf16 bf16s  __attribute__((may_alias));
typedef float  f32s   __attribute__((may_alias));

__device__ __forceinline__ float sigmoidf_(float x){ return 1.f/(1.f+__expf(-x)); }
__device__ __forceinline__ float tanhf_(float x){ float e = __expf(2.f*x); return 1.f - 2.f/(e+1.f); }

// XOR bank swizzle: permute 16B blocks within each row by row&7 (T2 recipe).
__device__ __forceinline__ char* swz(char* base, int row, int stride, int colb){
  return base + row*stride + (colb ^ ((row & 7) << 4));
}

// ---------------- weight prep: f32 -> bf16 transposed, W_m1@W_m2 collapsed ----------------
__global__ __launch_bounds__(256) void prep_kernel(
    const float* __restrict__ W_in,  const float* __restrict__ W_qkv,
    const float* __restrict__ W_m1,  const float* __restrict__ W_m2,
    const float* __restrict__ b_m1,  const float* __restrict__ b_m2,
    const float* __restrict__ W_gi,  const float* __restrict__ W_gm,
    __bf16* __restrict__ ws, float* __restrict__ bc)
{
  int gt = blockIdx.x*256 + threadIdx.x;
  int NT = gridDim.x*256;
  for (int i = gt; i < 128*128; i += NT){ int n=i>>7, k=i&127; ws[(WS_WIN >>1)+i] = (__bf16)W_in [k*128+n]; }
  for (int i = gt; i < 384*128; i += NT){ int n=i>>7, k=i&127; ws[(WS_WQKV>>1)+i] = (__bf16)W_qkv[k*384+n]; }
  for (int i = gt; i < 256*128; i += NT){ int n=i>>7, k=i&127; ws[(WS_WGI >>1)+i] = (__bf16)W_gi [k*256+n]; }
  for (int i = gt; i < 256*128; i += NT){ int n=i>>7, k=i&127; ws[(WS_WGM >>1)+i] = (__bf16)W_gm [k*256+n]; }
  for (int i = gt; i < 128*128; i += NT){
    int n=i>>7, k=i&127;
    float s = 0.f;
    for (int j=0;j<128;j++) s += W_m1[k*128+j]*W_m2[j*128+n];
    ws[(WS_WC>>1)+i] = (__bf16)s;
  }
  for (int i = gt; i < 128; i += NT){
    float s = b_m2[i];
    for (int j=0;j<128;j++) s += b_m1[j]*W_m2[j*128+i];
    bc[i] = s;
  }
}

// ---------------- fused main kernel (block-cooperative) ----------------
// launch_bounds(256,4): 4 blocks/CU. P2/P6 m-split so peak arch-VGPR fits the 64-reg
// split file (R11's residual 87MB spill was P2's aQ[3][4]=48 + acc overflow).
// Spill tripwire: WRITE_SIZE must be ~262144 KB (pure output).
__global__ __launch_bounds__(256, 4) void rmc_kernel(
    const float* __restrict__ inputs, const float* __restrict__ memory,
    const float* __restrict__ b_in,   const float* __restrict__ b_qkv,
    const float* __restrict__ lnq_g,  const float* __restrict__ lnq_b,
    const float* __restrict__ ln1_g,  const float* __restrict__ ln1_b,
    const float* __restrict__ ln2_g,  const float* __restrict__ ln2_b,
    const float* __restrict__ b_gi,   const float* __restrict__ b_gm,
    const __bf16* __restrict__ wWin,  const __bf16* __restrict__ wWqkv,
    const __bf16* __restrict__ wWc,   const __bf16* __restrict__ wWgi,
    const __bf16* __restrict__ wWgm,  const float* __restrict__ bc,
    float* __restrict__ out0, float* __restrict__ out1)
{
  __shared__ __align__(16) char smem[LDSSZ];
  char* Q = smem;
  char* A = smem + A_OFF;
  char* X = smem + X_OFF;

  const int tid  = threadIdx.x;
  const int lane = tid & 63;
  const int wv   = tid >> 6;
  const int l15  = lane & 15;
  const int lg   = lane >> 4;
  const int b0   = blockIdx.x * BT;
  const float QSC = 0.1020620726159658f;   // 96^-0.5

  // ---- P0: stage inputs (X rows 0..3) & memory (amp rows s*9+j) ----
  if (tid < 64){
    int r = tid >> 4, c = tid & 15;
    const float* gp = inputs + (size_t)(b0+r)*128 + c*8;
    f32x4 a = *(const f32x4*)gp, b = *(const f32x4*)(gp+4);
    bf16x8 h;
    h[0]=(__bf16)a[0]; h[1]=(__bf16)a[1]; h[2]=(__bf16)a[2]; h[3]=(__bf16)a[3];
    h[4]=(__bf16)b[0]; h[5]=(__bf16)b[1]; h[6]=(__bf16)b[2]; h[7]=(__bf16)b[3];
    *(bf16x8*)swz(X, r, 256, c*16) = h;
  }
  for (int t = tid; t < 512; t += 256){            // memory: 32 rows x 16 chunks
    int r = t >> 4, c8 = (t & 15)*8;
    const float* gp = memory + (size_t)(b0 + (r>>3))*1024 + (r&7)*128 + c8;
    f32x4 a = *(const f32x4*)gp, b = *(const f32x4*)(gp+4);
    bf16x8 h;
    h[0]=(__bf16)a[0]; h[1]=(__bf16)a[1]; h[2]=(__bf16)a[2]; h[3]=(__bf16)a[3];
    h[4]=(__bf16)b[0]; h[5]=(__bf16)b[1]; h[6]=(__bf16)b[2]; h[7]=(__bf16)b[3];
    *(bf16x8*)swz(A, (r>>3)*S1 + (r&7), 256, c8*2) = h;
  }
  __syncthreads();

  // ---- P1: x = inputs @ W_in + b_in   (M=4 valid rows, clamped A-tile) ----
  {
    const int xr = (l15 < BT) ? l15 : (BT-1);
    bf16x8 aX[4];
#pragma unroll
    for (int k=0;k<4;k++) aX[k] = *(const bf16x8*)swz(X, xr, 256, k*64 + lg*16);
    f32x4 accX[2];
#pragma unroll
    for (int n=0;n<2;n++){
      int nt = wv*2 + n;
      f32x4 acc = {0.f,0.f,0.f,0.f};
#pragma unroll
      for (int k=0;k<4;k++){
        bf16x8 b = *(const bf16x8*)(wWin + (nt*16 + l15)*128 + k*32 + 8*lg);
        acc = __builtin_amdgcn_mfma_f32_16x16x32_bf16(aX[k], b, acc, 0, 0, 0);
      }
      accX[n] = acc;
    }
    __syncthreads();   // all A-reads of X done before overwrite
#pragma unroll
    for (int n=0;n<2;n++){
#pragma unroll
      for (int r=0;r<4;r++){
        int row = 4*lg + r;
        if (row < BT){
          int col = (wv*2+n)*16 + l15;
          __bf16 h = (__bf16)(accX[n][r] + b_in[col]);
          *(bf16s*)swz(X, row, 256, col*2) = h;            // x (for gi GEMM)
          *(bf16s*)swz(A, row*S1+8, 256, col*2) = h;       // mp slot 8
        }
      }
    }
  }
  __syncthreads();

  // ---- P2: qkv_pre = mp @ W_qkv + b_qkv  (M=36; m-groups {0,1} and {2}) ----
  {
    // m-group {0,1}: aQ 32 arch regs + accQ 48 AGPR
    {
      bf16x8 aQ[2][4];
#pragma unroll
      for (int mi=0; mi<2; ++mi){
        int ar = mi*16 + l15; ar = (ar < RROWS) ? ar : (RROWS-1);
#pragma unroll
        for (int k=0;k<4;k++)
          aQ[mi][k] = *(const bf16x8*)swz(A, ar, 256, k*64 + lg*16);
      }
      f32x4 accQ[2][6];
#pragma unroll
      for (int mi=0;mi<2;mi++)
#pragma unroll
        for (int n=0;n<6;n++) accQ[mi][n] = (f32x4){0.f,0.f,0.f,0.f};
#pragma unroll
      for (int n=0;n<6;n++){
        int nt = wv*6 + n;
#pragma unroll
        for (int k=0;k<4;k++){
          bf16x8 b = *(const bf16x8*)(wWqkv + (nt*16 + l15)*128 + k*32 + 8*lg);
#pragma unroll
          for (int mi=0;mi<2;mi++)
            accQ[mi][n] = __builtin_amdgcn_mfma_f32_16x16x32_bf16(aQ[mi][k], b, accQ[mi][n], 0, 0, 0);
        }
      }
#pragma unroll
      for (int mi=0;mi<2;mi++)
#pragma unroll
        for (int n=0;n<6;n++)
#pragma unroll
          for (int r=0;r<4;r++){
            int row = mi*16 + 4*lg + r;
            int col = (wv*6+n)*16 + l15;
            *(bf16s*)swz(Q, row, 768, col*2) = (__bf16)(accQ[mi][n][r] + b_qkv[col]);
          }
    }
    // m-group {2}: rows 32..35 valid
    {
      int ar = 32 + l15; ar = (ar < RROWS) ? ar : (RROWS-1);
      bf16x8 aQ[4];
#pragma unroll
      for (int k=0;k<4;k++)
        aQ[k] = *(const bf16x8*)swz(A, ar, 256, k*64 + lg*16);
      f32x4 accQ[6];
#pragma unroll
      for (int n=0;n<6;n++) accQ[n] = (f32x4){0.f,0.f,0.f,0.f};
#pragma unroll
      for (int n=0;n<6;n++){
        int nt = wv*6 + n;
#pragma unroll
        for (int k=0;k<4;k++){
          bf16x8 b = *(const bf16x8*)(wWqkv + (nt*16 + l15)*128 + k*32 + 8*lg);
          accQ[n] = __builtin_amdgcn_mfma_f32_16x16x32_bf16(aQ[k], b, accQ[n], 0, 0, 0);
        }
      }
#pragma unroll
      for (int n=0;n<6;n++)
#pragma unroll
        for (int r=0;r<4;r++){
          int row = 32 + 4*lg + r;
          if (row < RROWS){
            int col = (wv*6+n)*16 + l15;
            *(bf16s*)swz(Q, row, 768, col*2) = (__bf16)(accQ[n][r] + b_qkv[col]);
          }
        }
    }
  }
  __syncthreads();

  // ---- P3: LN(qkv) in place + fold q-scale 96^-0.5 ----
  {
    float gq[6], bq[6];
#pragma unroll
    for (int t=0;t<6;t++){ gq[t] = lnq_g[lane+64*t]; bq[t] = lnq_b[lane+64*t]; }
    for (int r = wv; r < RROWS; r += 4){
      float x[6]; float s = 0.f, sq = 0.f;
#pragma unroll
      for (int t=0;t<6;t++){
        x[t] = (float)*(const bf16s*)swz(Q, r, 768, (lane + 64*t)*2);
        s += x[t]; sq += x[t]*x[t];
      }
#pragma unroll
      for (int o=1;o<64;o<<=1){ s += __shfl_xor(s,o); sq += __shfl_xor(sq,o); }
      float mean = s * (1.f/384.f);
      float var  = sq * (1.f/384.f) - mean*mean;
      float rs   = rsqrtf(var + 1e-5f);
#pragma unroll
      for (int t=0;t<6;t++){
        int c = lane + 64*t;
        float y = gq[t]*(x[t]-mean)*rs + bq[t];
        if ((c % 96) < 32) y *= QSC;
        *(bf16s*)swz(Q, r, 768, c*2) = (__bf16)y;
      }
    }
  }
  __syncthreads();

  // ---- P4a: QK^T via 4 MFMAs per wave (wave = sample); softmax via 16-lane
  //      shuffles; P stored f32 into the wave's OWN dead q-slices (q consumed). ----
  {
    const int s = wv;
    const int arow = (l15 < 9) ? l15 : 8;          // clamp: valid in-slab rows only
    f32x4 sc[4];
#pragma unroll
    for (int h=0;h<4;h++){
      bf16x8 qa = *(const bf16x8*)swz(Q, s*S1+arow, 768, h*192 + lg*16);
      bf16x8 kb = *(const bf16x8*)swz(Q, s*S1+arow, 768, h*192 + 64 + lg*16);
      sc[h] = __builtin_amdgcn_mfma_f32_16x16x32_bf16(qa, kb, (f32x4){0.f,0.f,0.f,0.f}, 0, 0, 0);
    }
#pragma unroll
    for (int h=0;h<4;h++){
#pragma unroll
      for (int r=0;r<4;r++){
        int row = 4*lg + r;                        // q index
        float v = (l15 < 9) ? sc[h][r] : -1e30f;   // mask dup/pad k BEFORE use
        float mx = v;
#pragma unroll
        for (int o=1;o<16;o<<=1) mx = fmaxf(mx, __shfl_xor(mx, o));
        float p = __expf(v - mx);
        float sm = p;
#pragma unroll
        for (int o=1;o<16;o<<=1) sm += __shfl_xor(sm, o);
        float pn = p / sm;
        if (row < 9 && l15 < 9)
          *(f32s*)swz(Q, s*S1+row, 768, h*192 + l15*4) = pn;   // P -> own q-slice
      }
    }
  }
  __syncthreads();

  // ---- P4b: PV -> dead K-slices (cb+64..cb+128; K consumed by P4a's MFMA).
  //      Out bytes disjoint from P (cb..cb+36) and V (cb+128+): NO internal barriers. ----
  for (int t = tid; t < 576; t += 256){
    int s = t/144; int r2 = t%144;
    int h = r2/36;  int r3 = r2%36;
    int q = r3>>2;  int d16 = (r3&3)*16;
    int cb = h*192;
    float o8[8] = {0.f,0.f,0.f,0.f,0.f,0.f,0.f,0.f};
#pragma unroll
    for (int k=0;k<9;k++){
      float p = *(const f32s*)swz(Q, s*S1+q, 768, cb + k*4);
      bf16x8 v8 = *(const bf16x8*)swz(Q, s*S1+k, 768, cb + 128 + d16);
#pragma unroll
      for (int e=0;e<8;e++) o8[e] += p*(float)v8[e];
    }
    bf16x8 ho;
#pragma unroll
    for (int e=0;e<8;e++) ho[e] = (__bf16)o8[e];
    *(bf16x8*)swz(Q, s*S1+q, 768, cb + 64 + d16) = ho;   // out -> dead K-slice
  }
  __syncthreads();

  // ---- P5: mem = LN(mp + out) -> A in place (out read from K-slices) ----
  {
    float g0 = ln1_g[lane], g1 = ln1_g[lane+64], e0 = ln1_b[lane], e1 = ln1_b[lane+64];
    const int ob0 = (lane>>5)*192 + 64 + (lane&31)*2;          // out elem `lane`
    const int ob1 = ((lane>>5)+2)*192 + 64 + (lane&31)*2;      // out elem `lane+64`
    for (int r = wv; r < RROWS; r += 4){
      float t0 = (float)*(const bf16s*)swz(A, r, 256, lane*2)
               + (float)*(const bf16s*)swz(Q, r, 768, ob0);
      float t1 = (float)*(const bf16s*)swz(A, r, 256, (lane+64)*2)
               + (float)*(const bf16s*)swz(Q, r, 768, ob1);
      float s = t0+t1, sq = t0*t0 + t1*t1;
#pragma unroll
      for (int o=1;o<64;o<<=1){ s += __shfl_xor(s,o); sq += __shfl_xor(sq,o); }
      float mean = s*(1.f/128.f), var = sq*(1.f/128.f) - mean*mean;
      float rs = rsqrtf(var + 1e-5f);
      *(bf16s*)swz(A, r, 256, lane*2)      = (__bf16)(g0*(t0-mean)*rs + e0);
      *(bf16s*)swz(A, r, 256, (lane+64)*2) = (__bf16)(g1*(t1-mean)*rs + e1);
    }
  }
  __syncthreads();

  // ---- P6: mlp = mem @ (W_m1 W_m2) + bc -> Q f32 [36][512] swz (m-groups) ----
  {
    f32x4 accM0[2][2];   // m-group {0,1}
    {
      bf16x8 aM[2][4];
#pragma unroll
      for (int mi=0; mi<2; ++mi){
        int ar = mi*16 + l15; ar = (ar < RROWS) ? ar : (RROWS-1);
#pragma unroll
        for (int k=0;k<4;k++)
          aM[mi][k] = *(const bf16x8*)swz(A, ar, 256, k*64 + lg*16);
      }
#pragma unroll
      for (int mi=0;mi<2;mi++)
#pragma unroll
        for (int n=0;n<2;n++) accM0[mi][n] = (f32x4){0.f,0.f,0.f,0.f};
#pragma unroll
      for (int n=0;n<2;n++){
        int nt = wv*2 + n;
#pragma unroll
        for (int k=0;k<4;k++){
          bf16x8 b = *(const bf16x8*)(wWc + (nt*16 + l15)*128 + k*32 + 8*lg);
#pragma unroll
          for (int mi=0;mi<2;mi++)
            accM0[mi][n] = __builtin_amdgcn_mfma_f32_16x16x32_bf16(aM[mi][k], b, accM0[mi][n], 0, 0, 0);
        }
      }
    }
    f32x4 accM2[2];      // m-group {2}
    {
      int ar = 32 + l15; ar = (ar < RROWS) ? ar : (RROWS-1);
      bf16x8 aM[4];
#pragma unroll
      for (int k=0;k<4;k++)
        aM[k] = *(const bf16x8*)swz(A, ar, 256, k*64 + lg*16);
#pragma unroll
      for (int n=0;n<2;n++) accM2[n] = (f32x4){0.f,0.f,0.f,0.f};
#pragma unroll
      for (int n=0;n<2;n++){
        int nt = wv*2 + n;
#pragma unroll
        for (int k=0;k<4;k++){
          bf16x8 b = *(const bf16x8*)(wWc + (nt*16 + l15)*128 + k*32 + 8*lg);
          accM2[n] = __builtin_amdgcn_mfma_f32_16x16x32_bf16(aM[k], b, accM2[n], 0, 0, 0);
        }
      }
    }
    __syncthreads();   // Q (qkv+P+out) fully consumed (P5) before overwrite as mlp
#pragma unroll
    for (int mi=0;mi<2;mi++)
#pragma unroll
      for (int n=0;n<2;n++)
#pragma unroll
        for (int r=0;r<4;r++){
          int row = mi*16 + 4*lg + r;
          int col = (wv*2+n)*16 + l15;
          *(f32s*)swz(Q, row, 512, col*4) = accM0[mi][n][r] + bc[col];
        }
#pragma unroll
    for (int n=0;n<2;n++)
#pragma unroll
      for (int r=0;r<4;r++){
        int row = 32 + 4*lg + r;
        if (row < RROWS){
          int col = (wv*2+n)*16 + l15;
          *(f32s*)swz(Q, row, 512, col*4) = accM2[n][r] + bc[col];
        }
      }
  }
  __syncthreads();

  // ---- P7: mem2 = LN(mlp + mem) -> Q+MEM2 bf16 compact [32][256] (skip slot-8) ----
  {
    float g0 = ln2_g[lane], g1 = ln2_g[lane+64], e0 = ln2_b[lane], e1 = ln2_b[lane+64];
    for (int r = wv; r < RROWS; r += 4){
      if ((r % S1) == 8) continue;
      float t0 = *(const f32s*)swz(Q, r, 512, lane*4)
               + (float)*(const bf16s*)swz(A, r, 256, lane*2);
      float t1 = *(const f32s*)swz(Q, r, 512, (lane+64)*4)
               + (float)*(const bf16s*)swz(A, r, 256, (lane+64)*2);
      float s = t0+t1, sq = t0*t0 + t1*t1;
#pragma unroll
      for (int o=1;o<64;o<<=1){ s += __shfl_xor(s,o); sq += __shfl_xor(sq,o); }
      float mean = s*(1.f/128.f), var = sq*(1.f/128.f) - mean*mean;
      float rs = rsqrtf(var + 1e-5f);
      int rp = (r/S1)*8 + (r%S1);                          // compact row s*8+j
      *(bf16s*)swz(Q + MEM2, rp, 256, lane*2)      = (__bf16)(g0*(t0-mean)*rs + e0);
      *(bf16s*)swz(Q + MEM2, rp, 256, (lane+64)*2) = (__bf16)(g1*(t1-mean)*rs + e1);
    }
  }
  __syncthreads();

  // ---- P8: gi = x @ W_gi + b_gi -> gib f32 [4][1024] @Q (over dead mlp);
  //          tanh(memory) -> A compact rows 0..31 ----
  {
    const int xr = (l15 < BT) ? l15 : (BT-1);
    bf16x8 aG[4];
#pragma unroll
    for (int k=0;k<4;k++) aG[k] = *(const bf16x8*)swz(X, xr, 256, k*64 + lg*16);
    f32x4 accG[4];
#pragma unroll
    for (int n=0;n<4;n++) accG[n] = (f32x4){0.f,0.f,0.f,0.f};
#pragma unroll
    for (int n=0;n<4;n++){
      int nt = wv*4 + n;
#pragma unroll
      for (int k=0;k<4;k++){
        bf16x8 b = *(const bf16x8*)(wWgi + (nt*16 + l15)*128 + k*32 + 8*lg);
        accG[n] = __builtin_amdgcn_mfma_f32_16x16x32_bf16(aG[k], b, accG[n], 0, 0, 0);
      }
    }
#pragma unroll
    for (int n=0;n<4;n++)
#pragma unroll
      for (int r=0;r<4;r++){
        int row = 4*lg + r;
        if (row < BT){
          int col = (wv*4+n)*16 + l15;
          *(f32s*)swz(Q, row, 1024, col*4) = accG[n][r] + b_gi[col];
        }
      }
    for (int t = tid; t < 512; t += 256){
      int r = t >> 4, c8 = (t & 15)*8;
      const float* gp = memory + (size_t)(b0 + (r>>3))*1024 + (r&7)*128 + c8;
      f32x4 a = *(const f32x4*)gp, b = *(const f32x4*)(gp+4);
      bf16x8 h;
      h[0]=(__bf16)tanhf_(a[0]); h[1]=(__bf16)tanhf_(a[1]);
      h[2]=(__bf16)tanhf_(a[2]); h[3]=(__bf16)tanhf_(a[3]);
      h[4]=(__bf16)tanhf_(b[0]); h[5]=(__bf16)tanhf_(b[1]);
      h[6]=(__bf16)tanhf_(b[2]); h[7]=(__bf16)tanhf_(b[3]);
      *(bf16x8*)swz(A, r, 256, c8*2) = h;
    }
  }
  __syncthreads();

  // ---- P9: gm = tanh(memory) @ W_gm + b_gm; fused gates -> global.
  //      m outer, p inner, epilogue immediate (low register pressure). ----
  {
#pragma unroll
    for (int m=0;m<2;m++){
      bf16x8 aT[4];
#pragma unroll
      for (int k=0;k<4;k++)
        aT[k] = *(const bf16x8*)swz(A, m*16 + l15, 256, k*64 + lg*16);
#pragma unroll
      for (int p=0;p<2;p++){
        f32x4 ai = {0.f,0.f,0.f,0.f}, af = {0.f,0.f,0.f,0.f};
        int ntI = 2*wv + p, ntF = 8 + 2*wv + p;
#pragma unroll
        for (int k=0;k<4;k++){
          bf16x8 bI = *(const bf16x8*)(wWgm + (ntI*16 + l15)*128 + k*32 + 8*lg);
          bf16x8 bF = *(const bf16x8*)(wWgm + (ntF*16 + l15)*128 + k*32 + 8*lg);
          ai = __builtin_amdgcn_mfma_f32_16x16x32_bf16(aT[k], bI, ai, 0, 0, 0);
          af = __builtin_amdgcn_mfma_f32_16x16x32_bf16(aT[k], bF, af, 0, 0, 0);
        }
        int c = wv*32 + p*16 + l15;
        float bgi = b_gm[c], bgf = b_gm[128+c];
#pragma unroll
        for (int r=0;r<4;r++){
          int row = m*16 + 4*lg + r;       // 0..31 = s*8+j
          int s = row>>3, j = row&7;
          float g_i = ai[r] + bgi + *(const f32s*)swz(Q, s, 1024, c*4);
          float g_f = af[r] + bgf + *(const f32s*)swz(Q, s, 1024, (128+c)*4) + 1.0f;
          float ig = sigmoidf_(g_i), fg = sigmoidf_(g_f);
          float m2 = (float)*(const bf16s*)swz(Q + MEM2, row, 256, c*2);
          float mo = memory[(size_t)(b0+s)*1024 + j*128 + c];
          float nm = ig*tanhf_(m2) + fg*mo;
          size_t o = (size_t)(b0+s)*1024 + (size_t)(j*128 + c);
          out0[o] = nm;
          out1[o] = nm;
        }
      }
    }
  }
}

// ---------------- launch ----------------
extern "C" void kernel_launch(void* const* d_in, const int* in_sizes, int n_in,
                              void* d_out, int out_size, void* d_ws, size_t ws_size,
                              hipStream_t stream) {
  const float* inputs = (const float*)d_in[0];
  const float* memory = (const float*)d_in[1];
  const float* W_in   = (const float*)d_in[2];
  const float* b_in   = (const float*)d_in[3];
  const float* W_qkv  = (const float*)d_in[4];
  const float* b_qkv  = (const float*)d_in[5];
  const float* lnq_g  = (const float*)d_in[6];
  const float* lnq_b  = (const float*)d_in[7];
  const float* ln1_g  = (const float*)d_in[8];
  const float* ln1_b  = (const float*)d_in[9];
  const float* W_m1   = (const float*)d_in[10];
  const float* b_m1   = (const float*)d_in[11];
  const float* W_m2   = (const float*)d_in[12];
  const float* b_m2   = (const float*)d_in[13];
  const float* ln2_g  = (const float*)d_in[14];
  const float* ln2_b  = (const float*)d_in[15];
  const float* W_gi   = (const float*)d_in[16];
  const float* b_gi   = (const float*)d_in[17];
  const float* W_gm   = (const float*)d_in[18];
  const float* b_gm   = (const float*)d_in[19];

  __bf16* ws16 = (__bf16*)d_ws;
  float* bcp = (float*)((char*)d_ws + WS_BC);
  const __bf16* wWin  = (const __bf16*)((char*)d_ws + WS_WIN);
  const __bf16* wWqkv = (const __bf16*)((char*)d_ws + WS_WQKV);
  const __bf16* wWc   = (const __bf16*)((char*)d_ws + WS_WC);
  const __bf16* wWgi  = (const __bf16*)((char*)d_ws + WS_WGI);
  const __bf16* wWgm  = (const __bf16*)((char*)d_ws + WS_WGM);

  float* out0 = (float*)d_out;
  float* out1 = out0 + (size_t)BATCH*1024;

  prep_kernel<<<dim3(256), dim3(256), 0, stream>>>(
      W_in, W_qkv, W_m1, W_m2, b_m1, b_m2, W_gi, W_gm, ws16, bcp);

  rmc_kernel<<<dim3(NBLK), dim3(256), 0, stream>>>(
      inputs, memory, b_in, b_qkv, lnq_g, lnq_b, ln1_g, ln1_b, ln2_g, ln2_b,
      b_gi, b_gm, wWin, wWqkv, wWc, wWgi, wWgm, bcp, out0, out1);
}

// Round 13
// 552.222 us; speedup vs baseline: 1.1895x; 1.1895x over previous
//
#include <hip/hip_runtime.h>
#include <cstdint>
#include <cstddef>

// ---------------- constants ----------------
#define BATCH   32768
#define BT      4            // samples per workgroup
#define S1      9            // SLOTS+1
#define RROWS   36           // BT*S1
#define NBLK    (BATCH/BT)   // 8192

// d_ws byte offsets (bf16 transposed weights + collapsed MLP)
#define WS_WIN   0            // [128][128] bf16  WinT[n][k] = W_in[k][n]
#define WS_WQKV  32768        // [384][128] bf16
#define WS_WC    131072       // [128][128] bf16  (W_m1 @ W_m2)^T
#define WS_WGI   163840       // [256][128] bf16
#define WS_WGM   229376       // [256][128] bf16
#define WS_BC    294912       // [128] f32        b_m1 @ W_m2 + b_m2

// LDS plan (37888 B; 4 blocks/CU under launch_bounds(256,4)):
//  Q [0,27648)      qkv bf16 [36][768B] swz. P4a: P f32 (36B) into dead q-slices;
//                   P4b: attn-out bf16 (64B) into dead K-slices (cb+64). Later:
//                   mlp f32 [36][512B] @0 (P6); mem2 bf16 [32][256B] @19456 (P7);
//                   gib f32 [4][1024B] @0 (P8, over dead mlp rows 0..7).
//  A [27648,36864)  amp bf16 [36][256B] swz: mp -> mem (P5 in place) -> tanh(memory) (P8).
//  X [36864,37888)  x bf16 [4][256B] swz: staged inputs -> x (P1 in place).
// No zero padding: A-fragment rows CLAMPED (dups only feed discarded C rows).
#define A_OFF  27648
#define X_OFF  36864
#define MEM2   19456
#define LDSSZ  37888

typedef __bf16 bf16x8 __attribute__((ext_vector_type(8), may_alias));
typedef __bf16 bf16x4 __attribute__((ext_vector_type(4), may_alias));
typedef float  f32x4  __attribute__((ext_vector_type(4), may_alias));
typedef __bf16 bf16s  __attribute__((may_alias));
typedef float  f32s   __attribute__((may_alias));

__device__ __forceinline__ float sigmoidf_(float x){ return 1.f/(1.f+__expf(-x)); }
__device__ __forceinline__ float tanhf_(float x){ float e = __expf(2.f*x); return 1.f - 2.f/(e+1.f); }

// XOR bank swizzle: permute 16B blocks within each row by row&7 (T2 recipe).
__device__ __forceinline__ char* swz(char* base, int row, int stride, int colb){
  return base + row*stride + (colb ^ ((row & 7) << 4));
}

// ---------------- weight prep: f32 -> bf16 transposed, W_m1@W_m2 collapsed ----------------
__global__ __launch_bounds__(256) void prep_kernel(
    const float* __restrict__ W_in,  const float* __restrict__ W_qkv,
    const float* __restrict__ W_m1,  const float* __restrict__ W_m2,
    const float* __restrict__ b_m1,  const float* __restrict__ b_m2,
    const float* __restrict__ W_gi,  const float* __restrict__ W_gm,
    __bf16* __restrict__ ws, float* __restrict__ bc)
{
  int gt = blockIdx.x*256 + threadIdx.x;
  int NT = gridDim.x*256;
  for (int i = gt; i < 128*128; i += NT){ int n=i>>7, k=i&127; ws[(WS_WIN >>1)+i] = (__bf16)W_in [k*128+n]; }
  for (int i = gt; i < 384*128; i += NT){ int n=i>>7, k=i&127; ws[(WS_WQKV>>1)+i] = (__bf16)W_qkv[k*384+n]; }
  for (int i = gt; i < 256*128; i += NT){ int n=i>>7, k=i&127; ws[(WS_WGI >>1)+i] = (__bf16)W_gi [k*256+n]; }
  for (int i = gt; i < 256*128; i += NT){ int n=i>>7, k=i&127; ws[(WS_WGM >>1)+i] = (__bf16)W_gm [k*256+n]; }
  for (int i = gt; i < 128*128; i += NT){
    int n=i>>7, k=i&127;
    float s = 0.f;
    for (int j=0;j<128;j++) s += W_m1[k*128+j]*W_m2[j*128+n];
    ws[(WS_WC>>1)+i] = (__bf16)s;
  }
  for (int i = gt; i < 128; i += NT){
    float s = b_m2[i];
    for (int j=0;j<128;j++) s += b_m1[j]*W_m2[j*128+i];
    bc[i] = s;
  }
}

// ---------------- fused main kernel (block-cooperative, R11 structure) ----------------
__global__ __launch_bounds__(256, 4) void rmc_kernel(
    const float* __restrict__ inputs, const float* __restrict__ memory,
    const float* __restrict__ b_in,   const float* __restrict__ b_qkv,
    const float* __restrict__ lnq_g,  const float* __restrict__ lnq_b,
    const float* __restrict__ ln1_g,  const float* __restrict__ ln1_b,
    const float* __restrict__ ln2_g,  const float* __restrict__ ln2_b,
    const float* __restrict__ b_gi,   const float* __restrict__ b_gm,
    const __bf16* __restrict__ wWin,  const __bf16* __restrict__ wWqkv,
    const __bf16* __restrict__ wWc,   const __bf16* __restrict__ wWgi,
    const __bf16* __restrict__ wWgm,  const float* __restrict__ bc,
    float* __restrict__ out0, float* __restrict__ out1)
{
  __shared__ __align__(16) char smem[LDSSZ];
  char* Q = smem;
  char* A = smem + A_OFF;
  char* X = smem + X_OFF;

  const int tid  = threadIdx.x;
  const int lane = tid & 63;
  const int wv   = tid >> 6;
  const int l15  = lane & 15;
  const int lg   = lane >> 4;
  const int b0   = blockIdx.x * BT;
  const float QSC = 0.1020620726159658f;   // 96^-0.5

  // ---- P0: stage inputs (X rows 0..3) & memory (amp rows s*9+j) ----
  if (tid < 64){
    int r = tid >> 4, c = tid & 15;
    const float* gp = inputs + (size_t)(b0+r)*128 + c*8;
    f32x4 a = *(const f32x4*)gp, b = *(const f32x4*)(gp+4);
    bf16x8 h;
    h[0]=(__bf16)a[0]; h[1]=(__bf16)a[1]; h[2]=(__bf16)a[2]; h[3]=(__bf16)a[3];
    h[4]=(__bf16)b[0]; h[5]=(__bf16)b[1]; h[6]=(__bf16)b[2]; h[7]=(__bf16)b[3];
    *(bf16x8*)swz(X, r, 256, c*16) = h;
  }
  for (int t = tid; t < 512; t += 256){            // memory: 32 rows x 16 chunks
    int r = t >> 4, c8 = (t & 15)*8;
    const float* gp = memory + (size_t)(b0 + (r>>3))*1024 + (r&7)*128 + c8;
    f32x4 a = *(const f32x4*)gp, b = *(const f32x4*)(gp+4);
    bf16x8 h;
    h[0]=(__bf16)a[0]; h[1]=(__bf16)a[1]; h[2]=(__bf16)a[2]; h[3]=(__bf16)a[3];
    h[4]=(__bf16)b[0]; h[5]=(__bf16)b[1]; h[6]=(__bf16)b[2]; h[7]=(__bf16)b[3];
    *(bf16x8*)swz(A, (r>>3)*S1 + (r&7), 256, c8*2) = h;
  }
  __syncthreads();

  // ---- P1: x = inputs @ W_in + b_in   (M=4 valid rows, clamped A-tile) ----
  {
    const int xr = (l15 < BT) ? l15 : (BT-1);
    bf16x8 aX[4];
#pragma unroll
    for (int k=0;k<4;k++) aX[k] = *(const bf16x8*)swz(X, xr, 256, k*64 + lg*16);
    f32x4 accX[2];
#pragma unroll
    for (int n=0;n<2;n++){
      int nt = wv*2 + n;
      f32x4 acc = {0.f,0.f,0.f,0.f};
#pragma unroll
      for (int k=0;k<4;k++){
        bf16x8 b = *(const bf16x8*)(wWin + (nt*16 + l15)*128 + k*32 + 8*lg);
        acc = __builtin_amdgcn_mfma_f32_16x16x32_bf16(aX[k], b, acc, 0, 0, 0);
      }
      accX[n] = acc;
    }
    __syncthreads();   // all A-reads of X done before overwrite
#pragma unroll
    for (int n=0;n<2;n++){
#pragma unroll
      for (int r=0;r<4;r++){
        int row = 4*lg + r;
        if (row < BT){
          int col = (wv*2+n)*16 + l15;
          __bf16 h = (__bf16)(accX[n][r] + b_in[col]);
          *(bf16s*)swz(X, row, 256, col*2) = h;            // x (for gi GEMM)
          *(bf16s*)swz(A, row*S1+8, 256, col*2) = h;       // mp slot 8
        }
      }
    }
  }
  __syncthreads();

  // ---- P2: qkv_pre = mp @ W_qkv + b_qkv  (M=36, clamped A rows; n-loop halved) ----
  {
    bf16x8 aQ[3][4];
#pragma unroll
    for (int m=0;m<3;m++){
      int ar = m*16 + l15; ar = (ar < RROWS) ? ar : (RROWS-1);
#pragma unroll
      for (int k=0;k<4;k++)
        aQ[m][k] = *(const bf16x8*)swz(A, ar, 256, k*64 + lg*16);
    }
#pragma unroll
    for (int half=0; half<2; ++half){
      f32x4 accQ[3][3];
#pragma unroll
      for (int m=0;m<3;m++)
#pragma unroll
        for (int n=0;n<3;n++) accQ[m][n] = (f32x4){0.f,0.f,0.f,0.f};
#pragma unroll
      for (int n=0;n<3;n++){
        int nt = wv*6 + half*3 + n;
#pragma unroll
        for (int k=0;k<4;k++){
          bf16x8 b = *(const bf16x8*)(wWqkv + (nt*16 + l15)*128 + k*32 + 8*lg);
#pragma unroll
          for (int m=0;m<3;m++)
            accQ[m][n] = __builtin_amdgcn_mfma_f32_16x16x32_bf16(aQ[m][k], b, accQ[m][n], 0, 0, 0);
        }
      }
#pragma unroll
      for (int m=0;m<3;m++)
#pragma unroll
        for (int n=0;n<3;n++)
#pragma unroll
          for (int r=0;r<4;r++){
            int row = m*16 + 4*lg + r;
            if (row < RROWS){
              int col = (wv*6 + half*3 + n)*16 + l15;
              *(bf16s*)swz(Q, row, 768, col*2) = (__bf16)(accQ[m][n][r] + b_qkv[col]);
            }
          }
    }
  }
  __syncthreads();

  // ---- P3: LN(qkv) in place + fold q-scale 96^-0.5 ----
  {
    float gq[6], bq[6];
#pragma unroll
    for (int t=0;t<6;t++){ gq[t] = lnq_g[lane+64*t]; bq[t] = lnq_b[lane+64*t]; }
    for (int r = wv; r < RROWS; r += 4){
      float x[6]; float s = 0.f, sq = 0.f;
#pragma unroll
      for (int t=0;t<6;t++){
        x[t] = (float)*(const bf16s*)swz(Q, r, 768, (lane + 64*t)*2);
        s += x[t]; sq += x[t]*x[t];
      }
#pragma unroll
      for (int o=1;o<64;o<<=1){ s += __shfl_xor(s,o); sq += __shfl_xor(sq,o); }
      float mean = s * (1.f/384.f);
      float var  = sq * (1.f/384.f) - mean*mean;
      float rs   = rsqrtf(var + 1e-5f);
#pragma unroll
      for (int t=0;t<6;t++){
        int c = lane + 64*t;
        float y = gq[t]*(x[t]-mean)*rs + bq[t];
        if ((c % 96) < 32) y *= QSC;
        *(bf16s*)swz(Q, r, 768, c*2) = (__bf16)y;
      }
    }
  }
  __syncthreads();

  // ---- P4a: QK^T via 4 MFMAs per wave (wave = sample); softmax via 16-lane
  //      shuffles; P stored f32 into the wave's OWN dead q-slices (q consumed). ----
  {
    const int s = wv;
    const int arow = (l15 < 9) ? l15 : 8;          // clamp: valid in-slab rows only
    f32x4 sc[4];
#pragma unroll
    for (int h=0;h<4;h++){
      bf16x8 qa = *(const bf16x8*)swz(Q, s*S1+arow, 768, h*192 + lg*16);
      bf16x8 kb = *(const bf16x8*)swz(Q, s*S1+arow, 768, h*192 + 64 + lg*16);
      sc[h] = __builtin_amdgcn_mfma_f32_16x16x32_bf16(qa, kb, (f32x4){0.f,0.f,0.f,0.f}, 0, 0, 0);
    }
#pragma unroll
    for (int h=0;h<4;h++){
#pragma unroll
      for (int r=0;r<4;r++){
        int row = 4*lg + r;                        // q index
        float v = (l15 < 9) ? sc[h][r] : -1e30f;   // mask dup/pad k BEFORE use
        float mx = v;
#pragma unroll
        for (int o=1;o<16;o<<=1) mx = fmaxf(mx, __shfl_xor(mx, o));
        float p = __expf(v - mx);
        float sm = p;
#pragma unroll
        for (int o=1;o<16;o<<=1) sm += __shfl_xor(sm, o);
        float pn = p / sm;
        if (row < 9 && l15 < 9)
          *(f32s*)swz(Q, s*S1+row, 768, h*192 + l15*4) = pn;   // P -> own q-slice
      }
    }
  }
  __syncthreads();

  // ---- P4b: PV -> dead K-slices (cb+64..cb+128; K consumed by P4a's MFMA).
  //      Out bytes disjoint from P (cb..cb+36) and V (cb+128+): NO internal barriers. ----
  for (int t = tid; t < 576; t += 256){
    int s = t/144; int r2 = t%144;
    int h = r2/36;  int r3 = r2%36;
    int q = r3>>2;  int d16 = (r3&3)*16;
    int cb = h*192;
    float o8[8] = {0.f,0.f,0.f,0.f,0.f,0.f,0.f,0.f};
#pragma unroll
    for (int k=0;k<9;k++){
      float p = *(const f32s*)swz(Q, s*S1+q, 768, cb + k*4);
      bf16x8 v8 = *(const bf16x8*)swz(Q, s*S1+k, 768, cb + 128 + d16);
#pragma unroll
      for (int e=0;e<8;e++) o8[e] += p*(float)v8[e];
    }
    bf16x8 ho;
#pragma unroll
    for (int e=0;e<8;e++) ho[e] = (__bf16)o8[e];
    *(bf16x8*)swz(Q, s*S1+q, 768, cb + 64 + d16) = ho;   // out -> dead K-slice
  }
  __syncthreads();

  // ---- P5: mem = LN(mp + out) -> A in place (out read from K-slices).
  //      2 rows per wave-iteration, 32-lane reductions (halved shuffle chain). ----
  {
    const int half = lane >> 5;
    const int l31  = lane & 31;
    for (int base = wv*2; base < RROWS; base += 8){
      int r = base + half;
      float t[4]; float s = 0.f, sq = 0.f;
#pragma unroll
      for (int e=0;e<4;e++){
        int c = l31 + 32*e;
        float a = (float)*(const bf16s*)swz(A, r, 256, c*2)
                + (float)*(const bf16s*)swz(Q, r, 768, e*192 + 64 + l31*2);
        t[e] = a; s += a; sq += a*a;
      }
#pragma unroll
      for (int o=1;o<32;o<<=1){ s += __shfl_xor(s,o); sq += __shfl_xor(sq,o); }
      float mean = s*(1.f/128.f), var = sq*(1.f/128.f) - mean*mean;
      float rs = rsqrtf(var + 1e-5f);
#pragma unroll
      for (int e=0;e<4;e++){
        int c = l31 + 32*e;
        float y = ln1_g[c]*(t[e]-mean)*rs + ln1_b[c];
        *(bf16s*)swz(A, r, 256, c*2) = (__bf16)y;
      }
    }
  }
  __syncthreads();

  // ---- P6: mlp = mem @ (W_m1 W_m2) + bc -> Q f32 [36][512] swz (clamped A rows) ----
  {
    bf16x8 aM[3][4];
#pragma unroll
    for (int m=0;m<3;m++){
      int ar = m*16 + l15; ar = (ar < RROWS) ? ar : (RROWS-1);
#pragma unroll
      for (int k=0;k<4;k++)
        aM[m][k] = *(const bf16x8*)swz(A, ar, 256, k*64 + lg*16);
    }
    f32x4 accM[3][2];
#pragma unroll
    for (int m=0;m<3;m++)
#pragma unroll
      for (int n=0;n<2;n++) accM[m][n] = (f32x4){0.f,0.f,0.f,0.f};
#pragma unroll
    for (int n=0;n<2;n++){
      int nt = wv*2 + n;
#pragma unroll
      for (int k=0;k<4;k++){
        bf16x8 b = *(const bf16x8*)(wWc + (nt*16 + l15)*128 + k*32 + 8*lg);
#pragma unroll
        for (int m=0;m<3;m++)
          accM[m][n] = __builtin_amdgcn_mfma_f32_16x16x32_bf16(aM[m][k], b, accM[m][n], 0, 0, 0);
      }
    }
    __syncthreads();   // Q (qkv+P+out) fully consumed (P5) before overwrite as mlp
#pragma unroll
    for (int m=0;m<3;m++)
#pragma unroll
      for (int n=0;n<2;n++)
#pragma unroll
        for (int r=0;r<4;r++){
          int row = m*16 + 4*lg + r;
          if (row < RROWS){
            int col = (wv*2+n)*16 + l15;
            *(f32s*)swz(Q, row, 512, col*4) = accM[m][n][r] + bc[col];
          }
        }
  }
  __syncthreads();

  // ---- P7: mem2 = LN(mlp + mem) -> Q+MEM2 bf16 compact [32][256] (skip slot-8).
  //      2 rows per wave-iteration, 32-lane reductions. ----
  {
    const int half = lane >> 5;
    const int l31  = lane & 31;
    for (int base = wv*2; base < RROWS; base += 8){
      int r = base + half;
      if ((r % S1) != 8){
        float t[4]; float s = 0.f, sq = 0.f;
#pragma unroll
        for (int e=0;e<4;e++){
          int c = l31 + 32*e;
          float a = *(const f32s*)swz(Q, r, 512, c*4)
                  + (float)*(const bf16s*)swz(A, r, 256, c*2);
          t[e] = a; s += a; sq += a*a;
        }
#pragma unroll
        for (int o=1;o<32;o<<=1){ s += __shfl_xor(s,o); sq += __shfl_xor(sq,o); }
        float mean = s*(1.f/128.f), var = sq*(1.f/128.f) - mean*mean;
        float rs = rsqrtf(var + 1e-5f);
        int rp = (r/S1)*8 + (r%S1);                        // compact row s*8+j
#pragma unroll
        for (int e=0;e<4;e++){
          int c = l31 + 32*e;
          float y = ln2_g[c]*(t[e]-mean)*rs + ln2_b[c];
          *(bf16s*)swz(Q + MEM2, rp, 256, c*2) = (__bf16)y;
        }
      }
    }
  }
  __syncthreads();

  // ---- P8: gi = x @ W_gi + b_gi -> gib f32 [4][1024] @Q (over dead mlp);
  //          tanh(memory) -> A compact rows 0..31 ----
  {
    const int xr = (l15 < BT) ? l15 : (BT-1);
    bf16x8 aG[4];
#pragma unroll
    for (int k=0;k<4;k++) aG[k] = *(const bf16x8*)swz(X, xr, 256, k*64 + lg*16);
    f32x4 accG[4];
#pragma unroll
    for (int n=0;n<4;n++) accG[n] = (f32x4){0.f,0.f,0.f,0.f};
#pragma unroll
    for (int n=0;n<4;n++){
      int nt = wv*4 + n;
#pragma unroll
      for (int k=0;k<4;k++){
        bf16x8 b = *(const bf16x8*)(wWgi + (nt*16 + l15)*128 + k*32 + 8*lg);
        accG[n] = __builtin_amdgcn_mfma_f32_16x16x32_bf16(aG[k], b, accG[n], 0, 0, 0);
      }
    }
#pragma unroll
    for (int n=0;n<4;n++)
#pragma unroll
      for (int r=0;r<4;r++){
        int row = 4*lg + r;
        if (row < BT){
          int col = (wv*4+n)*16 + l15;
          *(f32s*)swz(Q, row, 1024, col*4) = accG[n][r] + b_gi[col];
        }
      }
    for (int t = tid; t < 512; t += 256){
      int r = t >> 4, c8 = (t & 15)*8;
      const float* gp = memory + (size_t)(b0 + (r>>3))*1024 + (r&7)*128 + c8;
      f32x4 a = *(const f32x4*)gp, b = *(const f32x4*)(gp+4);
      bf16x8 h;
      h[0]=(__bf16)tanhf_(a[0]); h[1]=(__bf16)tanhf_(a[1]);
      h[2]=(__bf16)tanhf_(a[2]); h[3]=(__bf16)tanhf_(a[3]);
      h[4]=(__bf16)tanhf_(b[0]); h[5]=(__bf16)tanhf_(b[1]);
      h[6]=(__bf16)tanhf_(b[2]); h[7]=(__bf16)tanhf_(b[3]);
      *(bf16x8*)swz(A, r, 256, c8*2) = h;
    }
  }
  __syncthreads();

  // ---- P9: gm = tanh(memory) @ W_gm + b_gm; fused gates -> global.
  //      m outer, p inner, epilogue immediate (low register pressure). ----
  {
#pragma unroll
    for (int m=0;m<2;m++){
      bf16x8 aT[4];
#pragma unroll
      for (int k=0;k<4;k++)
        aT[k] = *(const bf16x8*)swz(A, m*16 + l15, 256, k*64 + lg*16);
#pragma unroll
      for (int p=0;p<2;p++){
        f32x4 ai = {0.f,0.f,0.f,0.f}, af = {0.f,0.f,0.f,0.f};
        int ntI = 2*wv + p, ntF = 8 + 2*wv + p;
#pragma unroll
        for (int k=0;k<4;k++){
          bf16x8 bI = *(const bf16x8*)(wWgm + (ntI*16 + l15)*128 + k*32 + 8*lg);
          bf16x8 bF = *(const bf16x8*)(wWgm + (ntF*16 + l15)*128 + k*32 + 8*lg);
          ai = __builtin_amdgcn_mfma_f32_16x16x32_bf16(aT[k], bI, ai, 0, 0, 0);
          af = __builtin_amdgcn_mfma_f32_16x16x32_bf16(aT[k], bF, af, 0, 0, 0);
        }
        int c = wv*32 + p*16 + l15;
        float bgi = b_gm[c], bgf = b_gm[128+c];
#pragma unroll
        for (int r=0;r<4;r++){
          int row = m*16 + 4*lg + r;       // 0..31 = s*8+j
          int s = row>>3, j = row&7;
          float g_i = ai[r] + bgi + *(const f32s*)swz(Q, s, 1024, c*4);
          float g_f = af[r] + bgf + *(const f32s*)swz(Q, s, 1024, (128+c)*4) + 1.0f;
          float ig = sigmoidf_(g_i), fg = sigmoidf_(g_f);
          float m2 = (float)*(const bf16s*)swz(Q + MEM2, row, 256, c*2);
          float mo = memory[(size_t)(b0+s)*1024 + j*128 + c];
          float nm = ig*tanhf_(m2) + fg*mo;
          size_t o = (size_t)(b0+s)*1024 + (size_t)(j*128 + c);
          out0[o] = nm;
          out1[o] = nm;
        }
      }
    }
  }
}

// ---------------- launch ----------------
extern "C" void kernel_launch(void* const* d_in, const int* in_sizes, int n_in,
                              void* d_out, int out_size, void* d_ws, size_t ws_size,
                              hipStream_t stream) {
  const float* inputs = (const float*)d_in[0];
  const float* memory = (const float*)d_in[1];
  const float* W_in   = (const float*)d_in[2];
  const float* b_in   = (const float*)d_in[3];
  const float* W_qkv  = (const float*)d_in[4];
  const float* b_qkv  = (const float*)d_in[5];
  const float* lnq_g  = (const float*)d_in[6];
  const float* lnq_b  = (const float*)d_in[7];
  const float* ln1_g  = (const float*)d_in[8];
  const float* ln1_b  = (const float*)d_in[9];
  const float* W_m1   = (const float*)d_in[10];
  const float* b_m1   = (const float*)d_in[11];
  const float* W_m2   = (const float*)d_in[12];
  const float* b_m2   = (const float*)d_in[13];
  const float* ln2_g  = (const float*)d_in[14];
  const float* ln2_b  = (const float*)d_in[15];
  const float* W_gi   = (const float*)d_in[16];
  const float* b_gi   = (const float*)d_in[17];
  const float* W_gm   = (const float*)d_in[18];
  const float* b_gm   = (const float*)d_in[19];

  __bf16* ws16 = (__bf16*)d_ws;
  float* bcp = (float*)((char*)d_ws + WS_BC);
  const __bf16* wWin  = (const __bf16*)((char*)d_ws + WS_WIN);
  const __bf16* wWqkv = (const __bf16*)((char*)d_ws + WS_WQKV);
  const __bf16* wWc   = (const __bf16*)((char*)d_ws + WS_WC);
  const __bf16* wWgi  = (const __bf16*)((char*)d_ws + WS_WGI);
  const __bf16* wWgm  = (const __bf16*)((char*)d_ws + WS_WGM);

  float* out0 = (float*)d_out;
  float* out1 = out0 + (size_t)BATCH*1024;

  prep_kernel<<<dim3(256), dim3(256), 0, stream>>>(
      W_in, W_qkv, W_m1, W_m2, b_m1, b_m2, W_gi, W_gm, ws16, bcp);

  rmc_kernel<<<dim3(NBLK), dim3(256), 0, stream>>>(
      inputs, memory, b_in, b_qkv, lnq_g, lnq_b, ln1_g, ln1_b, ln2_g, ln2_b,
      b_gi, b_gm, wWin, wWqkv, wWc, wWgi, wWgm, bcp, out0, out1);
}

// Round 14
// 522.125 us; speedup vs baseline: 1.2581x; 1.0576x over previous
//
#include <hip/hip_runtime.h>
#include <cstdint>
#include <cstddef>

// ---------------- constants ----------------
#define BATCH   32768
#define BT      4            // samples per workgroup
#define S1      9            // SLOTS+1
#define RROWS   36           // BT*S1
#define NBLK    (BATCH/BT)   // 8192

// d_ws byte offsets (bf16 transposed weights + collapsed MLP)
#define WS_WIN   0            // [128][128] bf16  WinT[n][k] = W_in[k][n]
#define WS_WQKV  32768        // [384][128] bf16
#define WS_WC    131072       // [128][128] bf16  (W_m1 @ W_m2)^T
#define WS_WGI   163840       // [256][128] bf16
#define WS_WGM   229376       // [256][128] bf16
#define WS_BC    294912       // [128] f32        b_m1 @ W_m2 + b_m2

// LDS plan (37888 B; 4 blocks/CU under launch_bounds(256,4)):
//  Q [0,27648)      qkv bf16 [36][768B] swz. P4a: P f32 (36B) into dead q-slices;
//                   P4b: attn-out bf16 (64B) into dead K-slices (cb+64). Later:
//                   mlp f32 [36][512B] @0 (P6); mem2 bf16 [32][256B] @19456 (P7);
//                   gib f32 [4][1024B] @0 (P8, over dead mlp rows 0..7).
//  A [27648,36864)  amp bf16 [36][256B] swz: mp -> mem (P5 in place) -> tanh(memory) (P8).
//  X [36864,37888)  x bf16 [4][256B] swz: staged inputs -> x (P1 in place).
// No zero padding: A-fragment rows CLAMPED (dups only feed discarded C rows).
#define A_OFF  27648
#define X_OFF  36864
#define MEM2   19456
#define LDSSZ  37888

typedef __bf16 bf16x8 __attribute__((ext_vector_type(8), may_alias));
typedef __bf16 bf16x4 __attribute__((ext_vector_type(4), may_alias));
typedef float  f32x4  __attribute__((ext_vector_type(4), may_alias));
typedef __bf16 bf16s  __attribute__((may_alias));
typedef float  f32s   __attribute__((may_alias));

__device__ __forceinline__ float sigmoidf_(float x){ return 1.f/(1.f+__expf(-x)); }
__device__ __forceinline__ float tanhf_(float x){ float e = __expf(2.f*x); return 1.f - 2.f/(e+1.f); }

// XOR bank swizzle: permute 16B blocks within each row by row&7 (T2 recipe).
__device__ __forceinline__ char* swz(char* base, int row, int stride, int colb){
  return base + row*stride + (colb ^ ((row & 7) << 4));
}

// ---------------- weight prep: f32 -> bf16 transposed, W_m1@W_m2 collapsed ----------------
__global__ __launch_bounds__(256) void prep_kernel(
    const float* __restrict__ W_in,  const float* __restrict__ W_qkv,
    const float* __restrict__ W_m1,  const float* __restrict__ W_m2,
    const float* __restrict__ b_m1,  const float* __restrict__ b_m2,
    const float* __restrict__ W_gi,  const float* __restrict__ W_gm,
    __bf16* __restrict__ ws, float* __restrict__ bc)
{
  int gt = blockIdx.x*256 + threadIdx.x;
  int NT = gridDim.x*256;
  for (int i = gt; i < 128*128; i += NT){ int n=i>>7, k=i&127; ws[(WS_WIN >>1)+i] = (__bf16)W_in [k*128+n]; }
  for (int i = gt; i < 384*128; i += NT){ int n=i>>7, k=i&127; ws[(WS_WQKV>>1)+i] = (__bf16)W_qkv[k*384+n]; }
  for (int i = gt; i < 256*128; i += NT){ int n=i>>7, k=i&127; ws[(WS_WGI >>1)+i] = (__bf16)W_gi [k*256+n]; }
  for (int i = gt; i < 256*128; i += NT){ int n=i>>7, k=i&127; ws[(WS_WGM >>1)+i] = (__bf16)W_gm [k*256+n]; }
  for (int i = gt; i < 128*128; i += NT){
    int n=i>>7, k=i&127;
    float s = 0.f;
    for (int j=0;j<128;j++) s += W_m1[k*128+j]*W_m2[j*128+n];
    ws[(WS_WC>>1)+i] = (__bf16)s;
  }
  for (int i = gt; i < 128; i += NT){
    float s = b_m2[i];
    for (int j=0;j<128;j++) s += b_m1[j]*W_m2[j*128+i];
    bc[i] = s;
  }
}

// ---------------- fused main kernel (block-cooperative, R13 structure) ----------------
// launch_bounds(256,4): 4 blocks/CU, file split ~64 arch / 64 acc per wave.
// P2/P6 are k-OUTER so only a[3] (12 arch regs) of A-fragments is live at once;
// accumulators persist in AGPRs. Peak arch pressure <= ~40 everywhere -> no spills.
// Spill tripwire: WRITE_SIZE must be ~262144 KB (pure output).
__global__ __launch_bounds__(256, 4) void rmc_kernel(
    const float* __restrict__ inputs, const float* __restrict__ memory,
    const float* __restrict__ b_in,   const float* __restrict__ b_qkv,
    const float* __restrict__ lnq_g,  const float* __restrict__ lnq_b,
    const float* __restrict__ ln1_g,  const float* __restrict__ ln1_b,
    const float* __restrict__ ln2_g,  const float* __restrict__ ln2_b,
    const float* __restrict__ b_gi,   const float* __restrict__ b_gm,
    const __bf16* __restrict__ wWin,  const __bf16* __restrict__ wWqkv,
    const __bf16* __restrict__ wWc,   const __bf16* __restrict__ wWgi,
    const __bf16* __restrict__ wWgm,  const float* __restrict__ bc,
    float* __restrict__ out0, float* __restrict__ out1)
{
  __shared__ __align__(16) char smem[LDSSZ];
  char* Q = smem;
  char* A = smem + A_OFF;
  char* X = smem + X_OFF;

  const int tid  = threadIdx.x;
  const int lane = tid & 63;
  const int wv   = tid >> 6;
  const int l15  = lane & 15;
  const int lg   = lane >> 4;
  const int b0   = blockIdx.x * BT;
  const float QSC = 0.1020620726159658f;   // 96^-0.5

  // ---- P0: stage inputs (X rows 0..3) & memory (amp rows s*9+j) ----
  if (tid < 64){
    int r = tid >> 4, c = tid & 15;
    const float* gp = inputs + (size_t)(b0+r)*128 + c*8;
    f32x4 a = *(const f32x4*)gp, b = *(const f32x4*)(gp+4);
    bf16x8 h;
    h[0]=(__bf16)a[0]; h[1]=(__bf16)a[1]; h[2]=(__bf16)a[2]; h[3]=(__bf16)a[3];
    h[4]=(__bf16)b[0]; h[5]=(__bf16)b[1]; h[6]=(__bf16)b[2]; h[7]=(__bf16)b[3];
    *(bf16x8*)swz(X, r, 256, c*16) = h;
  }
  for (int t = tid; t < 512; t += 256){            // memory: 32 rows x 16 chunks
    int r = t >> 4, c8 = (t & 15)*8;
    const float* gp = memory + (size_t)(b0 + (r>>3))*1024 + (r&7)*128 + c8;
    f32x4 a = *(const f32x4*)gp, b = *(const f32x4*)(gp+4);
    bf16x8 h;
    h[0]=(__bf16)a[0]; h[1]=(__bf16)a[1]; h[2]=(__bf16)a[2]; h[3]=(__bf16)a[3];
    h[4]=(__bf16)b[0]; h[5]=(__bf16)b[1]; h[6]=(__bf16)b[2]; h[7]=(__bf16)b[3];
    *(bf16x8*)swz(A, (r>>3)*S1 + (r&7), 256, c8*2) = h;
  }
  __syncthreads();

  // ---- P1: x = inputs @ W_in + b_in   (M=4 valid rows, clamped A-tile) ----
  {
    const int xr = (l15 < BT) ? l15 : (BT-1);
    bf16x8 aX[4];
#pragma unroll
    for (int k=0;k<4;k++) aX[k] = *(const bf16x8*)swz(X, xr, 256, k*64 + lg*16);
    f32x4 accX[2];
#pragma unroll
    for (int n=0;n<2;n++){
      int nt = wv*2 + n;
      f32x4 acc = {0.f,0.f,0.f,0.f};
#pragma unroll
      for (int k=0;k<4;k++){
        bf16x8 b = *(const bf16x8*)(wWin + (nt*16 + l15)*128 + k*32 + 8*lg);
        acc = __builtin_amdgcn_mfma_f32_16x16x32_bf16(aX[k], b, acc, 0, 0, 0);
      }
      accX[n] = acc;
    }
    __syncthreads();   // all A-reads of X done before overwrite
#pragma unroll
    for (int n=0;n<2;n++){
#pragma unroll
      for (int r=0;r<4;r++){
        int row = 4*lg + r;
        if (row < BT){
          int col = (wv*2+n)*16 + l15;
          __bf16 h = (__bf16)(accX[n][r] + b_in[col]);
          *(bf16s*)swz(X, row, 256, col*2) = h;            // x (for gi GEMM)
          *(bf16s*)swz(A, row*S1+8, 256, col*2) = h;       // mp slot 8
        }
      }
    }
  }
  __syncthreads();

  // ---- P2: qkv_pre = mp @ W_qkv + b_qkv  (M=36, clamped A rows).
  //      n halved (acc[3][3]=36 AGPR) AND k-outer (aQ[3]=12 arch regs live). ----
  {
#pragma unroll
    for (int half=0; half<2; ++half){
      f32x4 accQ[3][3];
#pragma unroll
      for (int m=0;m<3;m++)
#pragma unroll
        for (int n=0;n<3;n++) accQ[m][n] = (f32x4){0.f,0.f,0.f,0.f};
#pragma unroll
      for (int kk=0; kk<4; ++kk){
        bf16x8 aQ[3];
#pragma unroll
        for (int m=0;m<3;m++){
          int ar = m*16 + l15; ar = (ar < RROWS) ? ar : (RROWS-1);
          aQ[m] = *(const bf16x8*)swz(A, ar, 256, kk*64 + lg*16);
        }
#pragma unroll
        for (int n=0;n<3;n++){
          int nt = wv*6 + half*3 + n;
          bf16x8 b = *(const bf16x8*)(wWqkv + (nt*16 + l15)*128 + kk*32 + 8*lg);
#pragma unroll
          for (int m=0;m<3;m++)
            accQ[m][n] = __builtin_amdgcn_mfma_f32_16x16x32_bf16(aQ[m], b, accQ[m][n], 0, 0, 0);
        }
      }
#pragma unroll
      for (int m=0;m<3;m++)
#pragma unroll
        for (int n=0;n<3;n++)
#pragma unroll
          for (int r=0;r<4;r++){
            int row = m*16 + 4*lg + r;
            if (row < RROWS){
              int col = (wv*6 + half*3 + n)*16 + l15;
              *(bf16s*)swz(Q, row, 768, col*2) = (__bf16)(accQ[m][n][r] + b_qkv[col]);
            }
          }
    }
  }
  __syncthreads();

  // ---- P3: LN(qkv) in place + fold q-scale 96^-0.5 ----
  {
    float gq[6], bq[6];
#pragma unroll
    for (int t=0;t<6;t++){ gq[t] = lnq_g[lane+64*t]; bq[t] = lnq_b[lane+64*t]; }
    for (int r = wv; r < RROWS; r += 4){
      float x[6]; float s = 0.f, sq = 0.f;
#pragma unroll
      for (int t=0;t<6;t++){
        x[t] = (float)*(const bf16s*)swz(Q, r, 768, (lane + 64*t)*2);
        s += x[t]; sq += x[t]*x[t];
      }
#pragma unroll
      for (int o=1;o<64;o<<=1){ s += __shfl_xor(s,o); sq += __shfl_xor(sq,o); }
      float mean = s * (1.f/384.f);
      float var  = sq * (1.f/384.f) - mean*mean;
      float rs   = rsqrtf(var + 1e-5f);
#pragma unroll
      for (int t=0;t<6;t++){
        int c = lane + 64*t;
        float y = gq[t]*(x[t]-mean)*rs + bq[t];
        if ((c % 96) < 32) y *= QSC;
        *(bf16s*)swz(Q, r, 768, c*2) = (__bf16)y;
      }
    }
  }
  __syncthreads();

  // ---- P4a: QK^T via 4 MFMAs per wave (wave = sample); softmax via 16-lane
  //      shuffles; P stored f32 into the wave's OWN dead q-slices (q consumed). ----
  {
    const int s = wv;
    const int arow = (l15 < 9) ? l15 : 8;          // clamp: valid in-slab rows only
    f32x4 sc[4];
#pragma unroll
    for (int h=0;h<4;h++){
      bf16x8 qa = *(const bf16x8*)swz(Q, s*S1+arow, 768, h*192 + lg*16);
      bf16x8 kb = *(const bf16x8*)swz(Q, s*S1+arow, 768, h*192 + 64 + lg*16);
      sc[h] = __builtin_amdgcn_mfma_f32_16x16x32_bf16(qa, kb, (f32x4){0.f,0.f,0.f,0.f}, 0, 0, 0);
    }
#pragma unroll
    for (int h=0;h<4;h++){
#pragma unroll
      for (int r=0;r<4;r++){
        int row = 4*lg + r;                        // q index
        float v = (l15 < 9) ? sc[h][r] : -1e30f;   // mask dup/pad k BEFORE use
        float mx = v;
#pragma unroll
        for (int o=1;o<16;o<<=1) mx = fmaxf(mx, __shfl_xor(mx, o));
        float p = __expf(v - mx);
        float sm = p;
#pragma unroll
        for (int o=1;o<16;o<<=1) sm += __shfl_xor(sm, o);
        float pn = p / sm;
        if (row < 9 && l15 < 9)
          *(f32s*)swz(Q, s*S1+row, 768, h*192 + l15*4) = pn;   // P -> own q-slice
      }
    }
  }
  __syncthreads();

  // ---- P4b: PV -> dead K-slices (cb+64..cb+128; K consumed by P4a's MFMA).
  //      Out bytes disjoint from P (cb..cb+36) and V (cb+128+): NO internal barriers. ----
  for (int t = tid; t < 576; t += 256){
    int s = t/144; int r2 = t%144;
    int h = r2/36;  int r3 = r2%36;
    int q = r3>>2;  int d16 = (r3&3)*16;
    int cb = h*192;
    float o8[8] = {0.f,0.f,0.f,0.f,0.f,0.f,0.f,0.f};
#pragma unroll
    for (int k=0;k<9;k++){
      float p = *(const f32s*)swz(Q, s*S1+q, 768, cb + k*4);
      bf16x8 v8 = *(const bf16x8*)swz(Q, s*S1+k, 768, cb + 128 + d16);
#pragma unroll
      for (int e=0;e<8;e++) o8[e] += p*(float)v8[e];
    }
    bf16x8 ho;
#pragma unroll
    for (int e=0;e<8;e++) ho[e] = (__bf16)o8[e];
    *(bf16x8*)swz(Q, s*S1+q, 768, cb + 64 + d16) = ho;   // out -> dead K-slice
  }
  __syncthreads();

  // ---- P5: mem = LN(mp + out) -> A in place (out read from K-slices).
  //      2 rows per wave-iteration, 32-lane reductions. ----
  {
    const int half = lane >> 5;
    const int l31  = lane & 31;
    for (int base = wv*2; base < RROWS; base += 8){
      int r = base + half;
      float t[4]; float s = 0.f, sq = 0.f;
#pragma unroll
      for (int e=0;e<4;e++){
        int c = l31 + 32*e;
        float a = (float)*(const bf16s*)swz(A, r, 256, c*2)
                + (float)*(const bf16s*)swz(Q, r, 768, e*192 + 64 + l31*2);
        t[e] = a; s += a; sq += a*a;
      }
#pragma unroll
      for (int o=1;o<32;o<<=1){ s += __shfl_xor(s,o); sq += __shfl_xor(sq,o); }
      float mean = s*(1.f/128.f), var = sq*(1.f/128.f) - mean*mean;
      float rs = rsqrtf(var + 1e-5f);
#pragma unroll
      for (int e=0;e<4;e++){
        int c = l31 + 32*e;
        float y = ln1_g[c]*(t[e]-mean)*rs + ln1_b[c];
        *(bf16s*)swz(A, r, 256, c*2) = (__bf16)y;
      }
    }
  }
  __syncthreads();

  // ---- P6: mlp = mem @ (W_m1 W_m2) + bc -> Q f32 [36][512] swz.
  //      k-outer: aM[3]=12 arch regs live; acc[3][2]=24 AGPR. ----
  {
    f32x4 accM[3][2];
#pragma unroll
    for (int m=0;m<3;m++)
#pragma unroll
      for (int n=0;n<2;n++) accM[m][n] = (f32x4){0.f,0.f,0.f,0.f};
#pragma unroll
    for (int kk=0; kk<4; ++kk){
      bf16x8 aM[3];
#pragma unroll
      for (int m=0;m<3;m++){
        int ar = m*16 + l15; ar = (ar < RROWS) ? ar : (RROWS-1);
        aM[m] = *(const bf16x8*)swz(A, ar, 256, kk*64 + lg*16);
      }
#pragma unroll
      for (int n=0;n<2;n++){
        int nt = wv*2 + n;
        bf16x8 b = *(const bf16x8*)(wWc + (nt*16 + l15)*128 + kk*32 + 8*lg);
#pragma unroll
        for (int m=0;m<3;m++)
          accM[m][n] = __builtin_amdgcn_mfma_f32_16x16x32_bf16(aM[m], b, accM[m][n], 0, 0, 0);
      }
    }
    __syncthreads();   // Q (qkv+P+out) fully consumed (P5) before overwrite as mlp
#pragma unroll
    for (int m=0;m<3;m++)
#pragma unroll
      for (int n=0;n<2;n++)
#pragma unroll
        for (int r=0;r<4;r++){
          int row = m*16 + 4*lg + r;
          if (row < RROWS){
            int col = (wv*2+n)*16 + l15;
            *(f32s*)swz(Q, row, 512, col*4) = accM[m][n][r] + bc[col];
          }
        }
  }
  __syncthreads();

  // ---- P7: mem2 = LN(mlp + mem) -> Q+MEM2 bf16 compact [32][256] (skip slot-8).
  //      2 rows per wave-iteration, 32-lane reductions. ----
  {
    const int half = lane >> 5;
    const int l31  = lane & 31;
    for (int base = wv*2; base < RROWS; base += 8){
      int r = base + half;
      if ((r % S1) != 8){
        float t[4]; float s = 0.f, sq = 0.f;
#pragma unroll
        for (int e=0;e<4;e++){
          int c = l31 + 32*e;
          float a = *(const f32s*)swz(Q, r, 512, c*4)
                  + (float)*(const bf16s*)swz(A, r, 256, c*2);
          t[e] = a; s += a; sq += a*a;
        }
#pragma unroll
        for (int o=1;o<32;o<<=1){ s += __shfl_xor(s,o); sq += __shfl_xor(sq,o); }
        float mean = s*(1.f/128.f), var = sq*(1.f/128.f) - mean*mean;
        float rs = rsqrtf(var + 1e-5f);
        int rp = (r/S1)*8 + (r%S1);                        // compact row s*8+j
#pragma unroll
        for (int e=0;e<4;e++){
          int c = l31 + 32*e;
          float y = ln2_g[c]*(t[e]-mean)*rs + ln2_b[c];
          *(bf16s*)swz(Q + MEM2, rp, 256, c*2) = (__bf16)y;
        }
      }
    }
  }
  __syncthreads();

  // ---- P8: gi = x @ W_gi + b_gi -> gib f32 [4][1024] @Q (over dead mlp);
  //          tanh(memory) -> A compact rows 0..31 ----
  {
    const int xr = (l15 < BT) ? l15 : (BT-1);
    bf16x8 aG[4];
#pragma unroll
    for (int k=0;k<4;k++) aG[k] = *(const bf16x8*)swz(X, xr, 256, k*64 + lg*16);
    f32x4 accG[4];
#pragma unroll
    for (int n=0;n<4;n++) accG[n] = (f32x4){0.f,0.f,0.f,0.f};
#pragma unroll
    for (int n=0;n<4;n++){
      int nt = wv*4 + n;
#pragma unroll
      for (int k=0;k<4;k++){
        bf16x8 b = *(const bf16x8*)(wWgi + (nt*16 + l15)*128 + k*32 + 8*lg);
        accG[n] = __builtin_amdgcn_mfma_f32_16x16x32_bf16(aG[k], b, accG[n], 0, 0, 0);
      }
    }
#pragma unroll
    for (int n=0;n<4;n++)
#pragma unroll
      for (int r=0;r<4;r++){
        int row = 4*lg + r;
        if (row < BT){
          int col = (wv*4+n)*16 + l15;
          *(f32s*)swz(Q, row, 1024, col*4) = accG[n][r] + b_gi[col];
        }
      }
    for (int t = tid; t < 512; t += 256){
      int r = t >> 4, c8 = (t & 15)*8;
      const float* gp = memory + (size_t)(b0 + (r>>3))*1024 + (r&7)*128 + c8;
      f32x4 a = *(const f32x4*)gp, b = *(const f32x4*)(gp+4);
      bf16x8 h;
      h[0]=(__bf16)tanhf_(a[0]); h[1]=(__bf16)tanhf_(a[1]);
      h[2]=(__bf16)tanhf_(a[2]); h[3]=(__bf16)tanhf_(a[3]);
      h[4]=(__bf16)tanhf_(b[0]); h[5]=(__bf16)tanhf_(b[1]);
      h[6]=(__bf16)tanhf_(b[2]); h[7]=(__bf16)tanhf_(b[3]);
      *(bf16x8*)swz(A, r, 256, c8*2) = h;
    }
  }
  __syncthreads();

  // ---- P9: gm = tanh(memory) @ W_gm + b_gm; fused gates -> global.
  //      m outer, p inner, epilogue immediate (low register pressure). ----
  {
#pragma unroll
    for (int m=0;m<2;m++){
      bf16x8 aT[4];
#pragma unroll
      for (int k=0;k<4;k++)
        aT[k] = *(const bf16x8*)swz(A, m*16 + l15, 256, k*64 + lg*16);
#pragma unroll
      for (int p=0;p<2;p++){
        f32x4 ai = {0.f,0.f,0.f,0.f}, af = {0.f,0.f,0.f,0.f};
        int ntI = 2*wv + p, ntF = 8 + 2*wv + p;
#pragma unroll
        for (int k=0;k<4;k++){
          bf16x8 bI = *(const bf16x8*)(wWgm + (ntI*16 + l15)*128 + k*32 + 8*lg);
          bf16x8 bF = *(const bf16x8*)(wWgm + (ntF*16 + l15)*128 + k*32 + 8*lg);
          ai = __builtin_amdgcn_mfma_f32_16x16x32_bf16(aT[k], bI, ai, 0, 0, 0);
          af = __builtin_amdgcn_mfma_f32_16x16x32_bf16(aT[k], bF, af, 0, 0, 0);
        }
        int c = wv*32 + p*16 + l15;
        float bgi = b_gm[c], bgf = b_gm[128+c];
#pragma unroll
        for (int r=0;r<4;r++){
          int row = m*16 + 4*lg + r;       // 0..31 = s*8+j
          int s = row>>3, j = row&7;
          float g_i = ai[r] + bgi + *(const f32s*)swz(Q, s, 1024, c*4);
          float g_f = af[r] + bgf + *(const f32s*)swz(Q, s, 1024, (128+c)*4) + 1.0f;
          float ig = sigmoidf_(g_i), fg = sigmoidf_(g_f);
          float m2 = (float)*(const bf16s*)swz(Q + MEM2, row, 256, c*2);
          float mo = memory[(size_t)(b0+s)*1024 + j*128 + c];
          float nm = ig*tanhf_(m2) + fg*mo;
          size_t o = (size_t)(b0+s)*1024 + (size_t)(j*128 + c);
          out0[o] = nm;
          out1[o] = nm;
        }
      }
    }
  }
}

// ---------------- launch ----------------
extern "C" void kernel_launch(void* const* d_in, const int* in_sizes, int n_in,
                              void* d_out, int out_size, void* d_ws, size_t ws_size,
                              hipStream_t stream) {
  const float* inputs = (const float*)d_in[0];
  const float* memory = (const float*)d_in[1];
  const float* W_in   = (const float*)d_in[2];
  const float* b_in   = (const float*)d_in[3];
  const float* W_qkv  = (const float*)d_in[4];
  const float* b_qkv  = (const float*)d_in[5];
  const float* lnq_g  = (const float*)d_in[6];
  const float* lnq_b  = (const float*)d_in[7];
  const float* ln1_g  = (const float*)d_in[8];
  const float* ln1_b  = (const float*)d_in[9];
  const float* W_m1   = (const float*)d_in[10];
  const float* b_m1   = (const float*)d_in[11];
  const float* W_m2   = (const float*)d_in[12];
  const float* b_m2   = (const float*)d_in[13];
  const float* ln2_g  = (const float*)d_in[14];
  const float* ln2_b  = (const float*)d_in[15];
  const float* W_gi   = (const float*)d_in[16];
  const float* b_gi   = (const float*)d_in[17];
  const float* W_gm   = (const float*)d_in[18];
  const float* b_gm   = (const float*)d_in[19];

  __bf16* ws16 = (__bf16*)d_ws;
  float* bcp = (float*)((char*)d_ws + WS_BC);
  const __bf16* wWin  = (const __bf16*)((char*)d_ws + WS_WIN);
  const __bf16* wWqkv = (const __bf16*)((char*)d_ws + WS_WQKV);
  const __bf16* wWc   = (const __bf16*)((char*)d_ws + WS_WC);
  const __bf16* wWgi  = (const __bf16*)((char*)d_ws + WS_WGI);
  const __bf16* wWgm  = (const __bf16*)((char*)d_ws + WS_WGM);

  float* out0 = (float*)d_out;
  float* out1 = out0 + (size_t)BATCH*1024;

  prep_kernel<<<dim3(256), dim3(256), 0, stream>>>(
      W_in, W_qkv, W_m1, W_m2, b_m1, b_m2, W_gi, W_gm, ws16, bcp);

  rmc_kernel<<<dim3(NBLK), dim3(256), 0, stream>>>(
      inputs, memory, b_in, b_qkv, lnq_g, lnq_b, ln1_g, ln1_b, ln2_g, ln2_b,
      b_gi, b_gm, wWin, wWqkv, wWc, wWgi, wWgm, bcp, out0, out1);
}